// Round 10
// baseline (231.863 us; speedup 1.0000x reference)
//
#include <hip/hip_runtime.h>
#include <hip/hip_bf16.h>

// ---------- types ----------
typedef short bf16x8 __attribute__((ext_vector_type(8)));   // 8 bf16 = 4 VGPR (MFMA A/B frag, K=32)
typedef float fx4    __attribute__((ext_vector_type(4)));   // MFMA C/D frag

#if __has_builtin(__builtin_amdgcn_exp2f)
#define EXP2 __builtin_amdgcn_exp2f
#else
#define EXP2 exp2f
#endif

// packed fp32x2 -> bf16x2 (RNE), emits v_cvt_pk_bf16_f32 on gfx950
__device__ __forceinline__ unsigned pk2(float a, float b) {
  union { __hip_bfloat162 h; unsigned u; } cv;
  cv.h = __float22bfloat162_rn(float2{a, b});
  return cv.u;
}
__device__ __forceinline__ uint2 pk4(const fx4& v) {
  uint2 r;
  r.x = pk2(v[0], v[1]);
  r.y = pk2(v[2], v[3]);
  return r;
}

// async global->LDS, 16B per lane. LDS dest = wave-uniform base + lane*16.
__device__ __forceinline__ void gld16(const void* g, void* l) {
  __builtin_amdgcn_global_load_lds(
      (const __attribute__((address_space(1))) unsigned int*)g,
      (__attribute__((address_space(3))) unsigned int*)l, 16, 0, 0);
}

// ---- barriers that do NOT drain vmcnt (keep register prefetches in flight) ----
__device__ __forceinline__ void bar_raw() {
  asm volatile("s_barrier" ::: "memory");
}
__device__ __forceinline__ void bar_lgkm() {
  asm volatile("s_waitcnt lgkmcnt(0)\ns_barrier" ::: "memory");
}
__device__ __forceinline__ void bar_lgkm_vm4() {
  asm volatile("s_waitcnt vmcnt(4) lgkmcnt(0)\ns_barrier" ::: "memory");
}
__device__ __forceinline__ void cfence() { asm volatile("" ::: "memory"); }

// ---------- prep: x cast + both weight transposes, one launch (R8 form) ----------
__global__ __launch_bounds__(256) void prep_kernel(
    const float* __restrict__ x, const float* __restrict__ Wq,
    const float* __restrict__ Wkv, const float* __restrict__ Wo,
    short* __restrict__ xb, short* __restrict__ WallT, short* __restrict__ WoT,
    float qscale) {
  const int bx = blockIdx.x, tid = threadIdx.x;
  if (bx < 4096) {
    int i = bx * 256 + tid;
    const float4 s = *(const float4*)(x + (size_t)i * 4);
    uint2 o; o.x = pk2(s.x, s.y); o.y = pk2(s.z, s.w);
    *(uint2*)(xb + (size_t)i * 4) = o;
    return;
  }
  __shared__ float t[32][33];
  const int idx = bx - 4096;            // 0..1023
  const int wb = idx & 63, kt = (idx >> 6) * 32;
  const bool mode0 = wb < 48;
  const int ct = (mode0 ? wb : wb - 48) * 32;
  const int tx = tid & 31, ty = tid >> 5;
  short* outT = mode0 ? WallT : WoT;
#pragma unroll
  for (int s = 0; s < 4; ++s) {
    int k = kt + ty + s * 8;
    int c = ct + tx;
    float v;
    if (mode0) v = (c < 512) ? Wq[(size_t)k * 512 + c] * qscale
                             : Wkv[(size_t)k * 1024 + (c - 512)];
    else       v = Wo[(size_t)k * 512 + c];
    t[ty + s * 8][tx] = v;
  }
  __syncthreads();
#pragma unroll
  for (int s = 0; s < 4; ++s) {
    int c = ct + ty + s * 8;
    int k = kt + tx;
    unsigned u = __float_as_uint(t[tx][ty + s * 8]);
    u = (u + 0x7fffu + ((u >> 16) & 1u)) >> 16;
    outT[(size_t)c * 512 + k] = (short)u;
  }
}

// ---------- QKV GEMM (R8 form): 128x128, BK=64, A reg-prefetch + B gld16/vm4 ----------
__global__ __launch_bounds__(256) void gemm_qkv(
    const short* __restrict__ A, const short* __restrict__ Bt,
    short* __restrict__ oq, short* __restrict__ ok, short* __restrict__ ovT) {
  __shared__ short As[2 * 128 * 32];   // [slab][row][32k]
  __shared__ short Bs[2 * 128 * 32];
  const int K = 512;
  const int tid = threadIdx.x;
  const int wave = tid >> 6, lane = tid & 63;
  const int quad = lane >> 4, l15 = lane & 15;
  const int wm = wave >> 1, wn = wave & 1;
  const int m0 = blockIdx.y * 128, n0 = blockIdx.x * 128;
  const bool swapped = (n0 < 1024);

  int arow[4], aoff[4];
#pragma unroll
  for (int c = 0; c < 4; ++c) {
    int u = c * 256 + tid;
    int slab = u >> 9, r2 = u & 511;
    arow[c] = r2 >> 2;
    aoff[c] = slab * 32 + (r2 & 3) * 8;
  }

  fx4 acc[4][4];
#pragma unroll
  for (int i = 0; i < 4; ++i)
#pragma unroll
    for (int j = 0; j < 4; ++j) acc[i][j] = fx4{0.f, 0.f, 0.f, 0.f};

  bf16x8 apre[4];
#pragma unroll
  for (int c = 0; c < 4; ++c)
    apre[c] = *(const bf16x8*)(A + (size_t)(m0 + arow[c]) * K + aoff[c]);

  for (int k0 = 0; k0 < K; k0 += 64) {
    bar_raw();
#pragma unroll
    for (int c = 0; c < 4; ++c)
      *(bf16x8*)(As + (size_t)(c * 256 + tid) * 8) = apre[c];
#pragma unroll
    for (int c = 0; c < 4; ++c) {
      int u = c * 256 + tid;
      int slab = u >> 9, r2 = u & 511;
      gld16(Bt + (size_t)(n0 + (r2 >> 2)) * K + k0 + slab * 32 + (r2 & 3) * 8,
            Bs + (size_t)(c * 256 + wave * 64) * 8);
    }
    cfence();
    {
      int kn = (k0 + 64) & 511;
#pragma unroll
      for (int c = 0; c < 4; ++c)
        apre[c] = *(const bf16x8*)(A + (size_t)(m0 + arow[c]) * K + kn + aoff[c]);
    }
    bar_lgkm_vm4();

#pragma unroll
    for (int ks2 = 0; ks2 < 2; ++ks2) {
      bf16x8 af[4], bfr[4];
#pragma unroll
      for (int i = 0; i < 4; ++i)
        af[i] = *(const bf16x8*)(As + ks2 * 4096 + (wm * 64 + i * 16 + l15) * 32 + quad * 8);
#pragma unroll
      for (int i = 0; i < 4; ++i)
        bfr[i] = *(const bf16x8*)(Bs + ks2 * 4096 + (wn * 64 + i * 16 + l15) * 32 + quad * 8);
      if (swapped) {
#pragma unroll
        for (int mi = 0; mi < 4; ++mi)
#pragma unroll
          for (int ni = 0; ni < 4; ++ni)
            acc[mi][ni] = __builtin_amdgcn_mfma_f32_16x16x32_bf16(bfr[ni], af[mi], acc[mi][ni], 0, 0, 0);
      } else {
#pragma unroll
        for (int mi = 0; mi < 4; ++mi)
#pragma unroll
          for (int ni = 0; ni < 4; ++ni)
            acc[mi][ni] = __builtin_amdgcn_mfma_f32_16x16x32_bf16(af[mi], bfr[ni], acc[mi][ni], 0, 0, 0);
      }
    }
  }

  const int rowb = m0 + wm * 64;
  const int colb = n0 + wn * 64;
  const int cls = n0 >> 9;  // 0=q, 1=k, 2=v
  if (cls < 2) {
    short* base = (cls == 0) ? oq : ok;
#pragma unroll
    for (int mi = 0; mi < 4; ++mi) {
      int t = rowb + mi * 16 + l15;
      int bb = t >> 11, ii = t & 2047;
#pragma unroll
      for (int ni = 0; ni < 4; ++ni) {
        int f = (colb + ni * 16 + quad * 4) & 511;
        int hh = f >> 6, dd = f & 63;
        *(uint2*)(base + ((size_t)(bb * 8 + hh) * 2048 + ii) * 64 + dd) = pk4(acc[mi][ni]);
      }
    }
  } else {
#pragma unroll
    for (int mi = 0; mi < 4; ++mi) {
      int rbase = rowb + mi * 16 + quad * 4;
      int bb = rbase >> 11;
      int ii = rbase & 2047;
#pragma unroll
      for (int ni = 0; ni < 4; ++ni) {
        int c = (colb + ni * 16 + l15) & 511;
        int hh = c >> 6, dd = c & 63;
        *(uint2*)(ovT + ((size_t)(bb * 8 + hh) * 64 + dd) * 2048 + ii) = pk4(acc[mi][ni]);
      }
    }
  }
}

// ---------- out-proj GEMM: 64x128 tile, BK=64, full reg-prefetch, fp32+bias ----------
__global__ __launch_bounds__(256) void gemm_out(
    const short* __restrict__ A, const short* __restrict__ Bt,
    float* __restrict__ of, const float* __restrict__ bias) {
  __shared__ short As[2 * 64 * 32];    // 8KB
  __shared__ short Bs[2 * 128 * 32];   // 16KB
  const int K = 512, N = 512;
  const int tid = threadIdx.x;
  const int wave = tid >> 6, lane = tid & 63;
  const int quad = lane >> 4, l15 = lane & 15;
  const int wm = wave >> 1, wn = wave & 1;
  const int m0 = blockIdx.y * 64, n0 = blockIdx.x * 128;

  int arow[2], aoff[2], brow[4], boff[4];
#pragma unroll
  for (int c = 0; c < 2; ++c) {
    int u = c * 256 + tid;
    int slab = u >> 8, r2 = u & 255;
    arow[c] = r2 >> 2; aoff[c] = slab * 32 + (r2 & 3) * 8;
  }
#pragma unroll
  for (int c = 0; c < 4; ++c) {
    int u = c * 256 + tid;
    int slab = u >> 9, r2 = u & 511;
    brow[c] = r2 >> 2; boff[c] = slab * 32 + (r2 & 3) * 8;
  }

  fx4 acc[2][4];
#pragma unroll
  for (int i = 0; i < 2; ++i)
#pragma unroll
    for (int j = 0; j < 4; ++j) acc[i][j] = fx4{0.f, 0.f, 0.f, 0.f};

  bf16x8 apre[2], bpre[4];
#pragma unroll
  for (int c = 0; c < 2; ++c)
    apre[c] = *(const bf16x8*)(A + (size_t)(m0 + arow[c]) * K + aoff[c]);
#pragma unroll
  for (int c = 0; c < 4; ++c)
    bpre[c] = *(const bf16x8*)(Bt + (size_t)(n0 + brow[c]) * K + boff[c]);

  for (int k0 = 0; k0 < K; k0 += 64) {
    bar_raw();
#pragma unroll
    for (int c = 0; c < 2; ++c)
      *(bf16x8*)(As + (size_t)(c * 256 + tid) * 8) = apre[c];
#pragma unroll
    for (int c = 0; c < 4; ++c)
      *(bf16x8*)(Bs + (size_t)(c * 256 + tid) * 8) = bpre[c];
    {
      int kn = (k0 + 64) & 511;
#pragma unroll
      for (int c = 0; c < 2; ++c)
        apre[c] = *(const bf16x8*)(A + (size_t)(m0 + arow[c]) * K + kn + aoff[c]);
#pragma unroll
      for (int c = 0; c < 4; ++c)
        bpre[c] = *(const bf16x8*)(Bt + (size_t)(n0 + brow[c]) * K + kn + boff[c]);
    }
    bar_lgkm();

#pragma unroll
    for (int ks2 = 0; ks2 < 2; ++ks2) {
      bf16x8 af[2], bfr[4];
#pragma unroll
      for (int i = 0; i < 2; ++i)
        af[i] = *(const bf16x8*)(As + ks2 * 2048 + (wm * 32 + i * 16 + l15) * 32 + quad * 8);
#pragma unroll
      for (int i = 0; i < 4; ++i)
        bfr[i] = *(const bf16x8*)(Bs + ks2 * 4096 + (wn * 64 + i * 16 + l15) * 32 + quad * 8);
#pragma unroll
      for (int mi = 0; mi < 2; ++mi)
#pragma unroll
        for (int ni = 0; ni < 4; ++ni)
          acc[mi][ni] = __builtin_amdgcn_mfma_f32_16x16x32_bf16(af[mi], bfr[ni], acc[mi][ni], 0, 0, 0);
    }
  }

  const int rowb = m0 + wm * 32;
  const int colb = n0 + wn * 64;
#pragma unroll
  for (int mi = 0; mi < 2; ++mi)
#pragma unroll
    for (int ni = 0; ni < 4; ++ni) {
      int cg = colb + ni * 16 + l15;
      float bv = bias[cg];
#pragma unroll
      for (int r = 0; r < 4; ++r) {
        int rg = rowb + mi * 16 + quad * 4 + r;
        of[(size_t)rg * N + cg] = acc[mi][ni][r] + bv;
      }
    }
}

// ---------- flash attention: NO STAGING, NO BARRIERS — direct-global K/V ----------
// Q,K: [bh=32][2048][64] bf16 ; Vt: [bh][64][2048] bf16 ; O: [b][2048][512] bf16
// grid (16 qtiles, 32 bh) = 512 blocks -> 2 blocks/CU, 8 waves/CU.
// kf/vf are natural b128 GLOBAL loads (K: 8 contiguous d at fixed j; Vt: 8
// contiguous j at fixed d) served from L1/L2 (per-XCD working set ~2MB fits L2;
// block-mates read identical addresses -> L1 hits). Only LDS use: wave-private
// P round-trip (C-layout -> B-frag) — no __syncthreads anywhere.
// kf software-pipelined one tile ahead; vf issued before QK for latency cover.
// Softmax: raw exp2 (log2-unit logits, fp32-safe; scale-free normalization).
__global__ __launch_bounds__(256) void attn_kernel(
    const short* __restrict__ Q, const short* __restrict__ K,
    const short* __restrict__ Vt, short* __restrict__ O) {
  __shared__ short Ps[4 * 32 * 72];    // per-wave P[i(32)][j(64)], stride 72

  const int tid = threadIdx.x;
  const int wave = tid >> 6, lane = tid & 63;
  const int quad = lane >> 4, l15 = lane & 15;
  const int bh = blockIdx.y;
  const int b = bh >> 3, h = bh & 7;
  const int i0 = blockIdx.x * 128 + wave * 32;
  short* Pw = Ps + wave * (32 * 72);

  const short* Kb = K + (size_t)bh * 2048 * 64;
  const short* Vb = Vt + (size_t)bh * 64 * 2048;

  // Q as B-operand fragments: [it][ks]; i = it*16+l15, d = ks*32+quad*8+e
  bf16x8 qf[2][2];
#pragma unroll
  for (int it = 0; it < 2; ++it)
#pragma unroll
    for (int ks = 0; ks < 2; ++ks)
      qf[it][ks] = *(const bf16x8*)(Q + ((size_t)bh * 2048 + i0 + it * 16 + l15) * 64 + ks * 32 + quad * 8);

  fx4 oacc[2][4];                      // [it][dt], O^T: row d=quad*4+r, col i=l15
  fx4 lacc[2] = { fx4{0.f,0.f,0.f,0.f}, fx4{0.f,0.f,0.f,0.f} };
#pragma unroll
  for (int it = 0; it < 2; ++it)
#pragma unroll
    for (int dt = 0; dt < 4; ++dt) oacc[it][dt] = fx4{0.f, 0.f, 0.f, 0.f};

  // kf pipeline: load tile 0's K fragments (A-operand: j = jt*16+l15 rows)
  bf16x8 kf[8];                        // [ks*4+jt]
#pragma unroll
  for (int ks = 0; ks < 2; ++ks)
#pragma unroll
    for (int jt = 0; jt < 4; ++jt)
      kf[ks * 4 + jt] = *(const bf16x8*)(Kb + (size_t)(jt * 16 + l15) * 64 + ks * 32 + quad * 8);

  for (int j0 = 0; j0 < 2048; j0 += 64) {
    // issue vf loads early (needed only after QK+softmax)
    bf16x8 vf[8];                      // [kj*4+dt]: V^T[d = dt*16+l15][j0 + kj*32+quad*8+e]
#pragma unroll
    for (int kj = 0; kj < 2; ++kj)
#pragma unroll
      for (int dt = 0; dt < 4; ++dt)
        vf[kj * 4 + dt] = *(const bf16x8*)(Vb + (size_t)(dt * 16 + l15) * 2048 + j0 + kj * 32 + quad * 8);

    // ---- S^T = K · Q^T ----
    fx4 s[2][4];
#pragma unroll
    for (int it = 0; it < 2; ++it)
#pragma unroll
      for (int jt = 0; jt < 4; ++jt) s[it][jt] = fx4{0.f, 0.f, 0.f, 0.f};
#pragma unroll
    for (int ks = 0; ks < 2; ++ks)
#pragma unroll
      for (int jt = 0; jt < 4; ++jt)
#pragma unroll
        for (int it = 0; it < 2; ++it)
          s[it][jt] = __builtin_amdgcn_mfma_f32_16x16x32_bf16(kf[ks * 4 + jt], qf[it][ks], s[it][jt], 0, 0, 0);

    // ---- p = exp2(s); accumulate l; P -> wave-private LDS (b64 writes) ----
#pragma unroll
    for (int it = 0; it < 2; ++it) {
#pragma unroll
      for (int jt = 0; jt < 4; ++jt) {
#pragma unroll
        for (int r = 0; r < 4; ++r) s[it][jt][r] = EXP2(s[it][jt][r]);
        *(uint2*)(Pw + (it * 16 + l15) * 72 + jt * 16 + quad * 4) = pk4(s[it][jt]);
      }
      lacc[it] += (s[it][0] + s[it][1]) + (s[it][2] + s[it][3]);
    }

    // ---- prefetch next tile's kf (overlaps PV) ----
    {
      int jn = (j0 + 64) & 2047;       // wrapped on last iter (harmless)
#pragma unroll
      for (int ks = 0; ks < 2; ++ks)
#pragma unroll
        for (int jt = 0; jt < 4; ++jt)
          kf[ks * 4 + jt] = *(const bf16x8*)(Kb + (size_t)(jn + jt * 16 + l15) * 64 + ks * 32 + quad * 8);
    }

    // ---- O^T += V^T · P^T (wave-private; lgkm wait auto-inserted) ----
#pragma unroll
    for (int kj = 0; kj < 2; ++kj) {
      bf16x8 pf[2];
#pragma unroll
      for (int it = 0; it < 2; ++it)
        pf[it] = *(const bf16x8*)(Pw + (it * 16 + l15) * 72 + kj * 32 + quad * 8);
#pragma unroll
      for (int dt = 0; dt < 4; ++dt)
#pragma unroll
        for (int it = 0; it < 2; ++it)
          oacc[it][dt] = __builtin_amdgcn_mfma_f32_16x16x32_bf16(vf[kj * 4 + dt], pf[it], oacc[it][dt], 0, 0, 0);
    }
  }

  // ---- normalize + write O bf16 [b][n=i][h*64+d]; 4 consecutive d -> b64 ----
#pragma unroll
  for (int it = 0; it < 2; ++it) {
    float l_s = (lacc[it][0] + lacc[it][1]) + (lacc[it][2] + lacc[it][3]);
    l_s += __shfl_xor(l_s, 16);
    l_s += __shfl_xor(l_s, 32);
    float inv = __builtin_amdgcn_rcpf(l_s);
    size_t rowbase = ((size_t)b * 2048 + i0 + it * 16 + l15) * 512 + h * 64;
#pragma unroll
    for (int dt = 0; dt < 4; ++dt) {
      fx4 o = oacc[it][dt] * inv;
      *(uint2*)(O + rowbase + dt * 16 + quad * 4) = pk4(o);
    }
  }
}

// ---------- launch ----------
extern "C" void kernel_launch(void* const* d_in, const int* in_sizes, int n_in,
                              void* d_out, int out_size, void* d_ws, size_t ws_size,
                              hipStream_t stream) {
  const float* x   = (const float*)d_in[0];
  const float* Wq  = (const float*)d_in[1];
  const float* Wkv = (const float*)d_in[2];
  const float* Wo  = (const float*)d_in[3];
  const float* bo  = (const float*)d_in[4];
  float* out = (float*)d_out;

  char* p = (char*)d_ws;
  short* xb    = (short*)p; p += (size_t)8192 * 512 * 2;   // x bf16 [8192,512]
  short* WallT = (short*)p; p += (size_t)1536 * 512 * 2;   // [Wq|Wkv]^T bf16 [1536,512]
  short* WoT   = (short*)p; p += (size_t)512 * 512 * 2;    // Wo^T bf16 [512,512]
  short* qb    = (short*)p; p += (size_t)32 * 2048 * 64 * 2;  // [bh,n,d]
  short* kb    = (short*)p; p += (size_t)32 * 2048 * 64 * 2;  // [bh,n,d]
  short* vTb   = (short*)p; p += (size_t)32 * 64 * 2048 * 2;  // [bh,d,n]
  short* Ob    = (short*)p; p += (size_t)8192 * 512 * 2;   // attn out bf16 [8192,512]

  const float qscale = 0.125f * 1.4426950408889634f;  // d^-0.5 * log2(e)

  prep_kernel<<<5120, 256, 0, stream>>>(x, Wq, Wkv, Wo, xb, WallT, WoT, qscale);
  gemm_qkv<<<dim3(12, 64), 256, 0, stream>>>(xb, WallT, qb, kb, vTb);
  attn_kernel<<<dim3(16, 32), 256, 0, stream>>>(qb, kb, vTb, Ob);
  gemm_out<<<dim3(4, 128), 256, 0, stream>>>(Ob, WoT, out, bo);
}

// Round 11
// 177.335 us; speedup vs baseline: 1.3075x; 1.3075x over previous
//
#include <hip/hip_runtime.h>
#include <hip/hip_bf16.h>

// ---------- types ----------
typedef short bf16x8 __attribute__((ext_vector_type(8)));   // 8 bf16 = 4 VGPR (MFMA A/B frag, K=32)
typedef float fx4    __attribute__((ext_vector_type(4)));   // MFMA C/D frag

#if __has_builtin(__builtin_amdgcn_exp2f)
#define EXP2 __builtin_amdgcn_exp2f
#else
#define EXP2 exp2f
#endif

// packed fp32x2 -> bf16x2 (RNE), emits v_cvt_pk_bf16_f32 on gfx950
__device__ __forceinline__ unsigned pk2(float a, float b) {
  union { __hip_bfloat162 h; unsigned u; } cv;
  cv.h = __float22bfloat162_rn(float2{a, b});
  return cv.u;
}
__device__ __forceinline__ uint2 pk4(const fx4& v) {
  uint2 r;
  r.x = pk2(v[0], v[1]);
  r.y = pk2(v[2], v[3]);
  return r;
}

// async global->LDS, 16B per lane. LDS dest = wave-uniform base + lane*16.
__device__ __forceinline__ void gld16(const void* g, void* l) {
  __builtin_amdgcn_global_load_lds(
      (const __attribute__((address_space(1))) unsigned int*)g,
      (__attribute__((address_space(3))) unsigned int*)l, 16, 0, 0);
}

// ---- barriers that do NOT drain vmcnt (keep register prefetches in flight) ----
__device__ __forceinline__ void bar_raw() {
  asm volatile("s_barrier" ::: "memory");
}
__device__ __forceinline__ void bar_lgkm() {
  asm volatile("s_waitcnt lgkmcnt(0)\ns_barrier" ::: "memory");
}
__device__ __forceinline__ void bar_lgkm_vm4() {
  asm volatile("s_waitcnt vmcnt(4) lgkmcnt(0)\ns_barrier" ::: "memory");
}
__device__ __forceinline__ void cfence() { asm volatile("" ::: "memory"); }

// ---------- prep: x cast + both weight transposes, one launch (R8 form) ----------
__global__ __launch_bounds__(256) void prep_kernel(
    const float* __restrict__ x, const float* __restrict__ Wq,
    const float* __restrict__ Wkv, const float* __restrict__ Wo,
    short* __restrict__ xb, short* __restrict__ WallT, short* __restrict__ WoT,
    float qscale) {
  const int bx = blockIdx.x, tid = threadIdx.x;
  if (bx < 4096) {
    int i = bx * 256 + tid;
    const float4 s = *(const float4*)(x + (size_t)i * 4);
    uint2 o; o.x = pk2(s.x, s.y); o.y = pk2(s.z, s.w);
    *(uint2*)(xb + (size_t)i * 4) = o;
    return;
  }
  __shared__ float t[32][33];
  const int idx = bx - 4096;            // 0..1023
  const int wb = idx & 63, kt = (idx >> 6) * 32;
  const bool mode0 = wb < 48;
  const int ct = (mode0 ? wb : wb - 48) * 32;
  const int tx = tid & 31, ty = tid >> 5;
  short* outT = mode0 ? WallT : WoT;
#pragma unroll
  for (int s = 0; s < 4; ++s) {
    int k = kt + ty + s * 8;
    int c = ct + tx;
    float v;
    if (mode0) v = (c < 512) ? Wq[(size_t)k * 512 + c] * qscale
                             : Wkv[(size_t)k * 1024 + (c - 512)];
    else       v = Wo[(size_t)k * 512 + c];
    t[ty + s * 8][tx] = v;
  }
  __syncthreads();
#pragma unroll
  for (int s = 0; s < 4; ++s) {
    int c = ct + ty + s * 8;
    int k = kt + tx;
    unsigned u = __float_as_uint(t[tx][ty + s * 8]);
    u = (u + 0x7fffu + ((u >> 16) & 1u)) >> 16;
    outT[(size_t)c * 512 + k] = (short)u;
  }
}

// ---------- QKV GEMM (R8 form): 128x128, BK=64, A reg-prefetch + B gld16/vm4 ----------
__global__ __launch_bounds__(256) void gemm_qkv(
    const short* __restrict__ A, const short* __restrict__ Bt,
    short* __restrict__ oq, short* __restrict__ ok, short* __restrict__ ovT) {
  __shared__ short As[2 * 128 * 32];   // [slab][row][32k]
  __shared__ short Bs[2 * 128 * 32];
  const int K = 512;
  const int tid = threadIdx.x;
  const int wave = tid >> 6, lane = tid & 63;
  const int quad = lane >> 4, l15 = lane & 15;
  const int wm = wave >> 1, wn = wave & 1;
  const int m0 = blockIdx.y * 128, n0 = blockIdx.x * 128;
  const bool swapped = (n0 < 1024);

  int arow[4], aoff[4];
#pragma unroll
  for (int c = 0; c < 4; ++c) {
    int u = c * 256 + tid;
    int slab = u >> 9, r2 = u & 511;
    arow[c] = r2 >> 2;
    aoff[c] = slab * 32 + (r2 & 3) * 8;
  }

  fx4 acc[4][4];
#pragma unroll
  for (int i = 0; i < 4; ++i)
#pragma unroll
    for (int j = 0; j < 4; ++j) acc[i][j] = fx4{0.f, 0.f, 0.f, 0.f};

  bf16x8 apre[4];
#pragma unroll
  for (int c = 0; c < 4; ++c)
    apre[c] = *(const bf16x8*)(A + (size_t)(m0 + arow[c]) * K + aoff[c]);

  for (int k0 = 0; k0 < K; k0 += 64) {
    bar_raw();
#pragma unroll
    for (int c = 0; c < 4; ++c)
      *(bf16x8*)(As + (size_t)(c * 256 + tid) * 8) = apre[c];
#pragma unroll
    for (int c = 0; c < 4; ++c) {
      int u = c * 256 + tid;
      int slab = u >> 9, r2 = u & 511;
      gld16(Bt + (size_t)(n0 + (r2 >> 2)) * K + k0 + slab * 32 + (r2 & 3) * 8,
            Bs + (size_t)(c * 256 + wave * 64) * 8);
    }
    cfence();
    {
      int kn = (k0 + 64) & 511;
#pragma unroll
      for (int c = 0; c < 4; ++c)
        apre[c] = *(const bf16x8*)(A + (size_t)(m0 + arow[c]) * K + kn + aoff[c]);
    }
    bar_lgkm_vm4();

#pragma unroll
    for (int ks2 = 0; ks2 < 2; ++ks2) {
      bf16x8 af[4], bfr[4];
#pragma unroll
      for (int i = 0; i < 4; ++i)
        af[i] = *(const bf16x8*)(As + ks2 * 4096 + (wm * 64 + i * 16 + l15) * 32 + quad * 8);
#pragma unroll
      for (int i = 0; i < 4; ++i)
        bfr[i] = *(const bf16x8*)(Bs + ks2 * 4096 + (wn * 64 + i * 16 + l15) * 32 + quad * 8);
      if (swapped) {
#pragma unroll
        for (int mi = 0; mi < 4; ++mi)
#pragma unroll
          for (int ni = 0; ni < 4; ++ni)
            acc[mi][ni] = __builtin_amdgcn_mfma_f32_16x16x32_bf16(bfr[ni], af[mi], acc[mi][ni], 0, 0, 0);
      } else {
#pragma unroll
        for (int mi = 0; mi < 4; ++mi)
#pragma unroll
          for (int ni = 0; ni < 4; ++ni)
            acc[mi][ni] = __builtin_amdgcn_mfma_f32_16x16x32_bf16(af[mi], bfr[ni], acc[mi][ni], 0, 0, 0);
      }
    }
  }

  const int rowb = m0 + wm * 64;
  const int colb = n0 + wn * 64;
  const int cls = n0 >> 9;  // 0=q, 1=k, 2=v
  if (cls < 2) {
    short* base = (cls == 0) ? oq : ok;
#pragma unroll
    for (int mi = 0; mi < 4; ++mi) {
      int t = rowb + mi * 16 + l15;
      int bb = t >> 11, ii = t & 2047;
#pragma unroll
      for (int ni = 0; ni < 4; ++ni) {
        int f = (colb + ni * 16 + quad * 4) & 511;
        int hh = f >> 6, dd = f & 63;
        *(uint2*)(base + ((size_t)(bb * 8 + hh) * 2048 + ii) * 64 + dd) = pk4(acc[mi][ni]);
      }
    }
  } else {
#pragma unroll
    for (int mi = 0; mi < 4; ++mi) {
      int rbase = rowb + mi * 16 + quad * 4;
      int bb = rbase >> 11;
      int ii = rbase & 2047;
#pragma unroll
      for (int ni = 0; ni < 4; ++ni) {
        int c = (colb + ni * 16 + l15) & 511;
        int hh = c >> 6, dd = c & 63;
        *(uint2*)(ovT + ((size_t)(bb * 8 + hh) * 64 + dd) * 2048 + ii) = pk4(acc[mi][ni]);
      }
    }
  }
}

// ---------- out-proj GEMM: 64x128 tile, BK=64, full reg-prefetch, fp32+bias ----------
__global__ __launch_bounds__(256) void gemm_out(
    const short* __restrict__ A, const short* __restrict__ Bt,
    float* __restrict__ of, const float* __restrict__ bias) {
  __shared__ short As[2 * 64 * 32];    // 8KB
  __shared__ short Bs[2 * 128 * 32];   // 16KB
  const int K = 512, N = 512;
  const int tid = threadIdx.x;
  const int wave = tid >> 6, lane = tid & 63;
  const int quad = lane >> 4, l15 = lane & 15;
  const int wm = wave >> 1, wn = wave & 1;
  const int m0 = blockIdx.y * 64, n0 = blockIdx.x * 128;

  int arow[2], aoff[2], brow[4], boff[4];
#pragma unroll
  for (int c = 0; c < 2; ++c) {
    int u = c * 256 + tid;
    int slab = u >> 8, r2 = u & 255;
    arow[c] = r2 >> 2; aoff[c] = slab * 32 + (r2 & 3) * 8;
  }
#pragma unroll
  for (int c = 0; c < 4; ++c) {
    int u = c * 256 + tid;
    int slab = u >> 9, r2 = u & 511;
    brow[c] = r2 >> 2; boff[c] = slab * 32 + (r2 & 3) * 8;
  }

  fx4 acc[2][4];
#pragma unroll
  for (int i = 0; i < 2; ++i)
#pragma unroll
    for (int j = 0; j < 4; ++j) acc[i][j] = fx4{0.f, 0.f, 0.f, 0.f};

  bf16x8 apre[2], bpre[4];
#pragma unroll
  for (int c = 0; c < 2; ++c)
    apre[c] = *(const bf16x8*)(A + (size_t)(m0 + arow[c]) * K + aoff[c]);
#pragma unroll
  for (int c = 0; c < 4; ++c)
    bpre[c] = *(const bf16x8*)(Bt + (size_t)(n0 + brow[c]) * K + boff[c]);

  for (int k0 = 0; k0 < K; k0 += 64) {
    bar_raw();
#pragma unroll
    for (int c = 0; c < 2; ++c)
      *(bf16x8*)(As + (size_t)(c * 256 + tid) * 8) = apre[c];
#pragma unroll
    for (int c = 0; c < 4; ++c)
      *(bf16x8*)(Bs + (size_t)(c * 256 + tid) * 8) = bpre[c];
    {
      int kn = (k0 + 64) & 511;
#pragma unroll
      for (int c = 0; c < 2; ++c)
        apre[c] = *(const bf16x8*)(A + (size_t)(m0 + arow[c]) * K + kn + aoff[c]);
#pragma unroll
      for (int c = 0; c < 4; ++c)
        bpre[c] = *(const bf16x8*)(Bt + (size_t)(n0 + brow[c]) * K + kn + boff[c]);
    }
    bar_lgkm();

#pragma unroll
    for (int ks2 = 0; ks2 < 2; ++ks2) {
      bf16x8 af[2], bfr[4];
#pragma unroll
      for (int i = 0; i < 2; ++i)
        af[i] = *(const bf16x8*)(As + ks2 * 2048 + (wm * 32 + i * 16 + l15) * 32 + quad * 8);
#pragma unroll
      for (int i = 0; i < 4; ++i)
        bfr[i] = *(const bf16x8*)(Bs + ks2 * 4096 + (wn * 64 + i * 16 + l15) * 32 + quad * 8);
#pragma unroll
      for (int mi = 0; mi < 2; ++mi)
#pragma unroll
        for (int ni = 0; ni < 4; ++ni)
          acc[mi][ni] = __builtin_amdgcn_mfma_f32_16x16x32_bf16(af[mi], bfr[ni], acc[mi][ni], 0, 0, 0);
    }
  }

  const int rowb = m0 + wm * 32;
  const int colb = n0 + wn * 64;
#pragma unroll
  for (int mi = 0; mi < 2; ++mi)
#pragma unroll
    for (int ni = 0; ni < 4; ++ni) {
      int cg = colb + ni * 16 + l15;
      float bv = bias[cg];
#pragma unroll
      for (int r = 0; r < 4; ++r) {
        int rg = rowb + mi * 16 + quad * 4 + r;
        of[(size_t)rg * N + cg] = acc[mi][ni][r] + bv;
      }
    }
}

// ---------- flash attention: 64 q-rows/wave (its=4), BJ=64, reg-prefetch ----------
// Q,K: [bh=32][2048][64] bf16 ; Vt: [bh][64][2048] bf16 ; O: [b][2048][512] bf16
// grid (8 qtiles, 32 bh) = 256 blocks -> 1 block/CU, 4 waves/CU, LDS ~53 KB.
// kf/vf LDS reads (the per-CU bottleneck) amortized over 4 16-row groups:
// per wave-tile 20 b128 + 16 b64 serve 64 rows (R8: 24 ops per 32 rows).
// Softmax: raw exp2 (log2-unit logits, fp32-safe; scale-free normalization);
// l = per-lane fx4 adds + 2 end shuffles. vm-preserving barriers (R6 machinery).
__global__ __launch_bounds__(256, 1) void attn_kernel(
    const short* __restrict__ Q, const short* __restrict__ K,
    const short* __restrict__ Vt, short* __restrict__ O) {
  __shared__ short Ks[64 * 64];        // [j][d], seg-swizzled (seg ^ row&7)
  __shared__ short Vs[64 * 64];        // [d][j], seg-swizzled
  __shared__ short Ps[4 * 64 * 72];    // per-wave P[i(64)][j(64)], stride 72

  const int tid = threadIdx.x;
  const int wave = tid >> 6, lane = tid & 63;
  const int quad = lane >> 4, l15 = lane & 15;
  const int bh = blockIdx.y;
  const int b = bh >> 3, h = bh & 7;
  const int i0 = blockIdx.x * 256 + wave * 64;
  short* Pw = Ps + wave * (64 * 72);

  const int idx0 = tid, idx1 = 256 + tid;
  const int row0 = idx0 >> 3, sg0 = (idx0 & 7) ^ (row0 & 7);
  const int row1 = idx1 >> 3, sg1 = (idx1 & 7) ^ (row1 & 7);
  const short* Kb = K + (size_t)bh * 2048 * 64;
  const short* Vb = Vt + (size_t)bh * 64 * 2048;

  // Q as B-operand fragments: [it][ks]; i = it*16+l15, d = ks*32+quad*8+e
  bf16x8 qf[4][2];
#pragma unroll
  for (int it = 0; it < 4; ++it)
#pragma unroll
    for (int ks = 0; ks < 2; ++ks)
      qf[it][ks] = *(const bf16x8*)(Q + ((size_t)bh * 2048 + i0 + it * 16 + l15) * 64 + ks * 32 + quad * 8);

  fx4 oacc[4][4];                      // [it][dt], O^T: row d=quad*4+r, col i=l15
  fx4 lacc[4];
#pragma unroll
  for (int it = 0; it < 4; ++it) {
    lacc[it] = fx4{0.f, 0.f, 0.f, 0.f};
#pragma unroll
    for (int dt = 0; dt < 4; ++dt) oacc[it][dt] = fx4{0.f, 0.f, 0.f, 0.f};
  }

  bf16x8 kpre0, kpre1, vpre0, vpre1;
  kpre0 = *(const bf16x8*)(Kb + (size_t)row0 * 64 + sg0 * 8);
  kpre1 = *(const bf16x8*)(Kb + (size_t)row1 * 64 + sg1 * 8);
  vpre0 = *(const bf16x8*)(Vb + (size_t)row0 * 2048 + sg0 * 8);
  vpre1 = *(const bf16x8*)(Vb + (size_t)row1 * 2048 + sg1 * 8);

  for (int j0 = 0; j0 < 2048; j0 += 64) {
    bar_raw();                         // prior tile's LDS reads complete
    *(bf16x8*)(Ks + idx0 * 8) = kpre0;
    *(bf16x8*)(Ks + idx1 * 8) = kpre1;
    *(bf16x8*)(Vs + idx0 * 8) = vpre0;
    *(bf16x8*)(Vs + idx1 * 8) = vpre1;
    cfence();
    {
      int jn = (j0 + 64) & 2047;       // wrapped prefetch on last iter (harmless)
      kpre0 = *(const bf16x8*)(Kb + (size_t)(jn + row0) * 64 + sg0 * 8);
      kpre1 = *(const bf16x8*)(Kb + (size_t)(jn + row1) * 64 + sg1 * 8);
      vpre0 = *(const bf16x8*)(Vb + (size_t)row0 * 2048 + jn + sg0 * 8);
      vpre1 = *(const bf16x8*)(Vb + (size_t)row1 * 2048 + jn + sg1 * 8);
    }
    bar_lgkm();                        // LDS writes visible; prefetch stays in flight

    // ---- S^T = K · Q^T : each kf read feeds FOUR 16-row groups ----
    fx4 s[4][4];
#pragma unroll
    for (int it = 0; it < 4; ++it)
#pragma unroll
      for (int jt = 0; jt < 4; ++jt) s[it][jt] = fx4{0.f, 0.f, 0.f, 0.f};
#pragma unroll
    for (int ks = 0; ks < 2; ++ks) {
#pragma unroll
      for (int jt = 0; jt < 4; ++jt) {
        bf16x8 kf = *(const bf16x8*)(Ks + (jt * 16 + l15) * 64 + (((ks * 4 + quad) ^ (l15 & 7)) * 8));
#pragma unroll
        for (int it = 0; it < 4; ++it)
          s[it][jt] = __builtin_amdgcn_mfma_f32_16x16x32_bf16(kf, qf[it][ks], s[it][jt], 0, 0, 0);
      }
    }

    // ---- p = exp2(s); accumulate l; P -> per-wave LDS (b64 writes) ----
#pragma unroll
    for (int it = 0; it < 4; ++it) {
#pragma unroll
      for (int jt = 0; jt < 4; ++jt) {
#pragma unroll
        for (int r = 0; r < 4; ++r) s[it][jt][r] = EXP2(s[it][jt][r]);
        *(uint2*)(Pw + (it * 16 + l15) * 72 + jt * 16 + quad * 4) = pk4(s[it][jt]);
      }
      lacc[it] += (s[it][0] + s[it][1]) + (s[it][2] + s[it][3]);
    }

    // ---- O^T += V^T · P^T : each vf read feeds four groups ----
#pragma unroll
    for (int kj = 0; kj < 2; ++kj) {
      bf16x8 pf[4];
#pragma unroll
      for (int it = 0; it < 4; ++it)
        pf[it] = *(const bf16x8*)(Pw + (it * 16 + l15) * 72 + kj * 32 + quad * 8);
#pragma unroll
      for (int dt = 0; dt < 4; ++dt) {
        bf16x8 vf = *(const bf16x8*)(Vs + (dt * 16 + l15) * 64 + (((kj * 4 + quad) ^ (l15 & 7)) * 8));
#pragma unroll
        for (int it = 0; it < 4; ++it)
          oacc[it][dt] = __builtin_amdgcn_mfma_f32_16x16x32_bf16(vf, pf[it], oacc[it][dt], 0, 0, 0);
      }
    }
  }

  // ---- normalize + write O bf16 [b][n=i][h*64+d]; 4 consecutive d -> b64 ----
#pragma unroll
  for (int it = 0; it < 4; ++it) {
    float l_s = (lacc[it][0] + lacc[it][1]) + (lacc[it][2] + lacc[it][3]);
    l_s += __shfl_xor(l_s, 16);
    l_s += __shfl_xor(l_s, 32);
    float inv = __builtin_amdgcn_rcpf(l_s);
    size_t rowbase = ((size_t)b * 2048 + i0 + it * 16 + l15) * 512 + h * 64;
#pragma unroll
    for (int dt = 0; dt < 4; ++dt) {
      fx4 o = oacc[it][dt] * inv;
      *(uint2*)(O + rowbase + dt * 16 + quad * 4) = pk4(o);
    }
  }
}

// ---------- launch ----------
extern "C" void kernel_launch(void* const* d_in, const int* in_sizes, int n_in,
                              void* d_out, int out_size, void* d_ws, size_t ws_size,
                              hipStream_t stream) {
  const float* x   = (const float*)d_in[0];
  const float* Wq  = (const float*)d_in[1];
  const float* Wkv = (const float*)d_in[2];
  const float* Wo  = (const float*)d_in[3];
  const float* bo  = (const float*)d_in[4];
  float* out = (float*)d_out;

  char* p = (char*)d_ws;
  short* xb    = (short*)p; p += (size_t)8192 * 512 * 2;   // x bf16 [8192,512]
  short* WallT = (short*)p; p += (size_t)1536 * 512 * 2;   // [Wq|Wkv]^T bf16 [1536,512]
  short* WoT   = (short*)p; p += (size_t)512 * 512 * 2;    // Wo^T bf16 [512,512]
  short* qb    = (short*)p; p += (size_t)32 * 2048 * 64 * 2;  // [bh,n,d]
  short* kb    = (short*)p; p += (size_t)32 * 2048 * 64 * 2;  // [bh,n,d]
  short* vTb   = (short*)p; p += (size_t)32 * 64 * 2048 * 2;  // [bh,d,n]
  short* Ob    = (short*)p; p += (size_t)8192 * 512 * 2;   // attn out bf16 [8192,512]

  const float qscale = 0.125f * 1.4426950408889634f;  // d^-0.5 * log2(e)

  prep_kernel<<<5120, 256, 0, stream>>>(x, Wq, Wkv, Wo, xb, WallT, WoT, qscale);
  gemm_qkv<<<dim3(12, 64), 256, 0, stream>>>(xb, WallT, qb, kb, vTb);
  attn_kernel<<<dim3(8, 32), 256, 0, stream>>>(qb, kb, vTb, Ob);
  gemm_out<<<dim3(4, 128), 256, 0, stream>>>(Ob, WoT, out, bo);
}

// Round 12
// 165.263 us; speedup vs baseline: 1.4030x; 1.0730x over previous
//
#include <hip/hip_runtime.h>
#include <hip/hip_bf16.h>

// ---------- types ----------
typedef short bf16x8 __attribute__((ext_vector_type(8)));   // 8 bf16 = 4 VGPR (MFMA A/B frag, K=32)
typedef float fx4    __attribute__((ext_vector_type(4)));   // MFMA C/D frag

#if __has_builtin(__builtin_amdgcn_exp2f)
#define EXP2 __builtin_amdgcn_exp2f
#else
#define EXP2 exp2f
#endif

// packed fp32x2 -> bf16x2 (RNE), emits v_cvt_pk_bf16_f32 on gfx950
__device__ __forceinline__ unsigned pk2(float a, float b) {
  union { __hip_bfloat162 h; unsigned u; } cv;
  cv.h = __float22bfloat162_rn(float2{a, b});
  return cv.u;
}
__device__ __forceinline__ uint2 pk4(const fx4& v) {
  uint2 r;
  r.x = pk2(v[0], v[1]);
  r.y = pk2(v[2], v[3]);
  return r;
}

// async global->LDS, 16B per lane. LDS dest = wave-uniform base + lane*16.
__device__ __forceinline__ void gld16(const void* g, void* l) {
  __builtin_amdgcn_global_load_lds(
      (const __attribute__((address_space(1))) unsigned int*)g,
      (__attribute__((address_space(3))) unsigned int*)l, 16, 0, 0);
}

// ---- barriers that do NOT drain vmcnt (keep register prefetches in flight) ----
__device__ __forceinline__ void bar_raw() {
  asm volatile("s_barrier" ::: "memory");
}
__device__ __forceinline__ void bar_lgkm() {
  asm volatile("s_waitcnt lgkmcnt(0)\ns_barrier" ::: "memory");
}
__device__ __forceinline__ void bar_lgkm_vm4() {
  asm volatile("s_waitcnt vmcnt(4) lgkmcnt(0)\ns_barrier" ::: "memory");
}
__device__ __forceinline__ void cfence() { asm volatile("" ::: "memory"); }

// ---------- prep: x cast + both weight transposes, one launch ----------
__global__ __launch_bounds__(256) void prep_kernel(
    const float* __restrict__ x, const float* __restrict__ Wq,
    const float* __restrict__ Wkv, const float* __restrict__ Wo,
    short* __restrict__ xb, short* __restrict__ WallT, short* __restrict__ WoT,
    float qscale) {
  const int bx = blockIdx.x, tid = threadIdx.x;
  if (bx < 4096) {
    int i = bx * 256 + tid;
    const float4 s = *(const float4*)(x + (size_t)i * 4);
    uint2 o; o.x = pk2(s.x, s.y); o.y = pk2(s.z, s.w);
    *(uint2*)(xb + (size_t)i * 4) = o;
    return;
  }
  __shared__ float t[32][33];
  const int idx = bx - 4096;            // 0..1023
  const int wb = idx & 63, kt = (idx >> 6) * 32;
  const bool mode0 = wb < 48;
  const int ct = (mode0 ? wb : wb - 48) * 32;
  const int tx = tid & 31, ty = tid >> 5;
  short* outT = mode0 ? WallT : WoT;
#pragma unroll
  for (int s = 0; s < 4; ++s) {
    int k = kt + ty + s * 8;
    int c = ct + tx;
    float v;
    if (mode0) v = (c < 512) ? Wq[(size_t)k * 512 + c] * qscale
                             : Wkv[(size_t)k * 1024 + (c - 512)];
    else       v = Wo[(size_t)k * 512 + c];
    t[ty + s * 8][tx] = v;
  }
  __syncthreads();
#pragma unroll
  for (int s = 0; s < 4; ++s) {
    int c = ct + ty + s * 8;
    int k = kt + tx;
    unsigned u = __float_as_uint(t[tx][ty + s * 8]);
    u = (u + 0x7fffu + ((u >> 16) & 1u)) >> 16;
    outT[(size_t)c * 512 + k] = (short)u;
  }
}

// ---------- QKV GEMM: 128x128, BK=64, A reg-prefetch + B gld16/vm4 ----------
// grid (64 m, 12 n): blocks sharing an A-tile (same m0) are stride-64 in linear
// id == 0 mod 8 -> same XCD -> A served from one XCD's L2 (locality heuristic).
__global__ __launch_bounds__(256) void gemm_qkv(
    const short* __restrict__ A, const short* __restrict__ Bt,
    short* __restrict__ oq, short* __restrict__ ok, short* __restrict__ ovT) {
  __shared__ short As[2 * 128 * 32];   // [slab][row][32k]
  __shared__ short Bs[2 * 128 * 32];
  const int K = 512;
  const int tid = threadIdx.x;
  const int wave = tid >> 6, lane = tid & 63;
  const int quad = lane >> 4, l15 = lane & 15;
  const int wm = wave >> 1, wn = wave & 1;
  const int m0 = blockIdx.x * 128, n0 = blockIdx.y * 128;
  const bool swapped = (n0 < 1024);

  int arow[4], aoff[4];
#pragma unroll
  for (int c = 0; c < 4; ++c) {
    int u = c * 256 + tid;
    int slab = u >> 9, r2 = u & 511;
    arow[c] = r2 >> 2;
    aoff[c] = slab * 32 + (r2 & 3) * 8;
  }

  fx4 acc[4][4];
#pragma unroll
  for (int i = 0; i < 4; ++i)
#pragma unroll
    for (int j = 0; j < 4; ++j) acc[i][j] = fx4{0.f, 0.f, 0.f, 0.f};

  bf16x8 apre[4];
#pragma unroll
  for (int c = 0; c < 4; ++c)
    apre[c] = *(const bf16x8*)(A + (size_t)(m0 + arow[c]) * K + aoff[c]);

  for (int k0 = 0; k0 < K; k0 += 64) {
    bar_raw();
#pragma unroll
    for (int c = 0; c < 4; ++c)
      *(bf16x8*)(As + (size_t)(c * 256 + tid) * 8) = apre[c];
#pragma unroll
    for (int c = 0; c < 4; ++c) {
      int u = c * 256 + tid;
      int slab = u >> 9, r2 = u & 511;
      gld16(Bt + (size_t)(n0 + (r2 >> 2)) * K + k0 + slab * 32 + (r2 & 3) * 8,
            Bs + (size_t)(c * 256 + wave * 64) * 8);
    }
    cfence();
    {
      int kn = (k0 + 64) & 511;
#pragma unroll
      for (int c = 0; c < 4; ++c)
        apre[c] = *(const bf16x8*)(A + (size_t)(m0 + arow[c]) * K + kn + aoff[c]);
    }
    bar_lgkm_vm4();

#pragma unroll
    for (int ks2 = 0; ks2 < 2; ++ks2) {
      bf16x8 af[4], bfr[4];
#pragma unroll
      for (int i = 0; i < 4; ++i)
        af[i] = *(const bf16x8*)(As + ks2 * 4096 + (wm * 64 + i * 16 + l15) * 32 + quad * 8);
#pragma unroll
      for (int i = 0; i < 4; ++i)
        bfr[i] = *(const bf16x8*)(Bs + ks2 * 4096 + (wn * 64 + i * 16 + l15) * 32 + quad * 8);
      if (swapped) {
#pragma unroll
        for (int mi = 0; mi < 4; ++mi)
#pragma unroll
          for (int ni = 0; ni < 4; ++ni)
            acc[mi][ni] = __builtin_amdgcn_mfma_f32_16x16x32_bf16(bfr[ni], af[mi], acc[mi][ni], 0, 0, 0);
      } else {
#pragma unroll
        for (int mi = 0; mi < 4; ++mi)
#pragma unroll
          for (int ni = 0; ni < 4; ++ni)
            acc[mi][ni] = __builtin_amdgcn_mfma_f32_16x16x32_bf16(af[mi], bfr[ni], acc[mi][ni], 0, 0, 0);
      }
    }
  }

  const int rowb = m0 + wm * 64;
  const int colb = n0 + wn * 64;
  const int cls = n0 >> 9;  // 0=q, 1=k, 2=v
  if (cls < 2) {
    short* base = (cls == 0) ? oq : ok;
#pragma unroll
    for (int mi = 0; mi < 4; ++mi) {
      int t = rowb + mi * 16 + l15;
      int bb = t >> 11, ii = t & 2047;
#pragma unroll
      for (int ni = 0; ni < 4; ++ni) {
        int f = (colb + ni * 16 + quad * 4) & 511;
        int hh = f >> 6, dd = f & 63;
        *(uint2*)(base + ((size_t)(bb * 8 + hh) * 2048 + ii) * 64 + dd) = pk4(acc[mi][ni]);
      }
    }
  } else {
#pragma unroll
    for (int mi = 0; mi < 4; ++mi) {
      int rbase = rowb + mi * 16 + quad * 4;
      int bb = rbase >> 11;
      int ii = rbase & 2047;
#pragma unroll
      for (int ni = 0; ni < 4; ++ni) {
        int c = (colb + ni * 16 + l15) & 511;
        int hh = c >> 6, dd = c & 63;
        *(uint2*)(ovT + ((size_t)(bb * 8 + hh) * 64 + dd) * 2048 + ii) = pk4(acc[mi][ni]);
      }
    }
  }
}

// ---------- out-proj GEMM: 64x128, BK=64, full reg-prefetch, fp32+bias ----------
// grid (128 m, 4 n): A-sharing blocks stride-128 == 0 mod 8 -> same XCD.
__global__ __launch_bounds__(256) void gemm_out(
    const short* __restrict__ A, const short* __restrict__ Bt,
    float* __restrict__ of, const float* __restrict__ bias) {
  __shared__ short As[2 * 64 * 32];    // 8KB
  __shared__ short Bs[2 * 128 * 32];   // 16KB
  const int K = 512, N = 512;
  const int tid = threadIdx.x;
  const int wave = tid >> 6, lane = tid & 63;
  const int quad = lane >> 4, l15 = lane & 15;
  const int wm = wave >> 1, wn = wave & 1;
  const int m0 = blockIdx.x * 64, n0 = blockIdx.y * 128;

  int arow[2], aoff[2], brow[4], boff[4];
#pragma unroll
  for (int c = 0; c < 2; ++c) {
    int u = c * 256 + tid;
    int slab = u >> 8, r2 = u & 255;
    arow[c] = r2 >> 2; aoff[c] = slab * 32 + (r2 & 3) * 8;
  }
#pragma unroll
  for (int c = 0; c < 4; ++c) {
    int u = c * 256 + tid;
    int slab = u >> 9, r2 = u & 511;
    brow[c] = r2 >> 2; boff[c] = slab * 32 + (r2 & 3) * 8;
  }

  fx4 acc[2][4];
#pragma unroll
  for (int i = 0; i < 2; ++i)
#pragma unroll
    for (int j = 0; j < 4; ++j) acc[i][j] = fx4{0.f, 0.f, 0.f, 0.f};

  bf16x8 apre[2], bpre[4];
#pragma unroll
  for (int c = 0; c < 2; ++c)
    apre[c] = *(const bf16x8*)(A + (size_t)(m0 + arow[c]) * K + aoff[c]);
#pragma unroll
  for (int c = 0; c < 4; ++c)
    bpre[c] = *(const bf16x8*)(Bt + (size_t)(n0 + brow[c]) * K + boff[c]);

  for (int k0 = 0; k0 < K; k0 += 64) {
    bar_raw();
#pragma unroll
    for (int c = 0; c < 2; ++c)
      *(bf16x8*)(As + (size_t)(c * 256 + tid) * 8) = apre[c];
#pragma unroll
    for (int c = 0; c < 4; ++c)
      *(bf16x8*)(Bs + (size_t)(c * 256 + tid) * 8) = bpre[c];
    {
      int kn = (k0 + 64) & 511;
#pragma unroll
      for (int c = 0; c < 2; ++c)
        apre[c] = *(const bf16x8*)(A + (size_t)(m0 + arow[c]) * K + kn + aoff[c]);
#pragma unroll
      for (int c = 0; c < 4; ++c)
        bpre[c] = *(const bf16x8*)(Bt + (size_t)(n0 + brow[c]) * K + kn + boff[c]);
    }
    bar_lgkm();

#pragma unroll
    for (int ks2 = 0; ks2 < 2; ++ks2) {
      bf16x8 af[2], bfr[4];
#pragma unroll
      for (int i = 0; i < 2; ++i)
        af[i] = *(const bf16x8*)(As + ks2 * 2048 + (wm * 32 + i * 16 + l15) * 32 + quad * 8);
#pragma unroll
      for (int i = 0; i < 4; ++i)
        bfr[i] = *(const bf16x8*)(Bs + ks2 * 4096 + (wn * 64 + i * 16 + l15) * 32 + quad * 8);
#pragma unroll
      for (int mi = 0; mi < 2; ++mi)
#pragma unroll
        for (int ni = 0; ni < 4; ++ni)
          acc[mi][ni] = __builtin_amdgcn_mfma_f32_16x16x32_bf16(af[mi], bfr[ni], acc[mi][ni], 0, 0, 0);
    }
  }

  const int rowb = m0 + wm * 32;
  const int colb = n0 + wn * 64;
#pragma unroll
  for (int mi = 0; mi < 2; ++mi)
#pragma unroll
    for (int ni = 0; ni < 4; ++ni) {
      int cg = colb + ni * 16 + l15;
      float bv = bias[cg];
#pragma unroll
      for (int r = 0; r < 4; ++r) {
        int rg = rowb + mi * 16 + quad * 4 + r;
        of[(size_t)rg * N + cg] = acc[mi][ni][r] + bv;
      }
    }
}

// ---------- flash attention: 32 q-rows/wave (its=2), BJ=128, reg-prefetch ----------
// Q,K: [bh=32][2048][64] bf16 ; Vt: [bh][64][2048] bf16 ; O: [b][2048][512] bf16
// grid (16 qtiles, 32 bh) = 512 blocks -> 2 blocks/CU (LDS 66.6 KB fits exactly 2).
// BJ=128 halves barrier count (16 iters) at MATCHED occupancy (R5's failure was
// occupancy loss; here grid demand == LDS capacity). R8-proven its=2 layout.
// Softmax: raw exp2 (log2-unit logits, fp32-safe; scale-free normalization);
// l = per-lane fx4 adds + 2 end shuffles. vm-preserving barriers.
__global__ __launch_bounds__(256) void attn_kernel(
    const short* __restrict__ Q, const short* __restrict__ K,
    const short* __restrict__ Vt, short* __restrict__ O) {
  __shared__ short Ks[128 * 64];       // [j][d], 8 segs/row, slot = seg ^ (row&7)
  __shared__ short Vs[64 * 128];       // [d][j], 16 segs/row, slot = seg ^ (row&15)
  __shared__ short Ps[4 * 32 * 136];   // per-wave P[i(32)][j(128)], stride 136

  const int tid = threadIdx.x;
  const int wave = tid >> 6, lane = tid & 63;
  const int quad = lane >> 4, l15 = lane & 15;
  const int bh = blockIdx.y;
  const int b = bh >> 3, h = bh & 7;
  const int i0 = blockIdx.x * 128 + wave * 32;
  short* Pw = Ps + wave * (32 * 136);

  // staging coordinates: 4 16B-units each for K and V per thread
  int krow[4], ksg[4], vrow[4], vsg[4];
#pragma unroll
  for (int c = 0; c < 4; ++c) {
    int u = c * 256 + tid;             // 0..1023
    krow[c] = u >> 3;  ksg[c] = (u & 7) ^ (krow[c] & 7);
    vrow[c] = u >> 4;  vsg[c] = (u & 15) ^ (vrow[c] & 15);
  }
  const short* Kb = K + (size_t)bh * 2048 * 64;
  const short* Vb = Vt + (size_t)bh * 64 * 2048;

  // Q as B-operand fragments: [it][ks]; i = it*16+l15, d = ks*32+quad*8+e
  bf16x8 qf[2][2];
#pragma unroll
  for (int it = 0; it < 2; ++it)
#pragma unroll
    for (int ks = 0; ks < 2; ++ks)
      qf[it][ks] = *(const bf16x8*)(Q + ((size_t)bh * 2048 + i0 + it * 16 + l15) * 64 + ks * 32 + quad * 8);

  fx4 oacc[2][4];                      // [it][dt], O^T: row d=quad*4+r, col i=l15
  fx4 lacc[2] = { fx4{0.f,0.f,0.f,0.f}, fx4{0.f,0.f,0.f,0.f} };
#pragma unroll
  for (int it = 0; it < 2; ++it)
#pragma unroll
    for (int dt = 0; dt < 4; ++dt) oacc[it][dt] = fx4{0.f, 0.f, 0.f, 0.f};

  // prefetch tile 0 into registers
  bf16x8 kpre[4], vpre[4];
#pragma unroll
  for (int c = 0; c < 4; ++c) {
    kpre[c] = *(const bf16x8*)(Kb + (size_t)krow[c] * 64 + ksg[c] * 8);
    vpre[c] = *(const bf16x8*)(Vb + (size_t)vrow[c] * 2048 + vsg[c] * 8);
  }

  for (int j0 = 0; j0 < 2048; j0 += 128) {
    bar_raw();                         // prior tile's LDS reads complete
#pragma unroll
    for (int c = 0; c < 4; ++c) {
      *(bf16x8*)(Ks + (size_t)(c * 256 + tid) * 8) = kpre[c];
      *(bf16x8*)(Vs + (size_t)(c * 256 + tid) * 8) = vpre[c];
    }
    cfence();
    {
      int jn = (j0 + 128) & 2047;      // wrapped prefetch on last iter (harmless)
#pragma unroll
      for (int c = 0; c < 4; ++c) {
        kpre[c] = *(const bf16x8*)(Kb + (size_t)(jn + krow[c]) * 64 + ksg[c] * 8);
        vpre[c] = *(const bf16x8*)(Vb + (size_t)vrow[c] * 2048 + jn + vsg[c] * 8);
      }
    }
    bar_lgkm();                        // LDS writes visible; prefetch stays in flight

    // ---- S^T = K · Q^T : each kf read feeds both 16-row groups ----
    fx4 s[2][8];
#pragma unroll
    for (int it = 0; it < 2; ++it)
#pragma unroll
      for (int jt = 0; jt < 8; ++jt) s[it][jt] = fx4{0.f, 0.f, 0.f, 0.f};
#pragma unroll
    for (int ks = 0; ks < 2; ++ks) {
#pragma unroll
      for (int jt = 0; jt < 8; ++jt) {
        bf16x8 kf = *(const bf16x8*)(Ks + (jt * 16 + l15) * 64 + (((ks * 4 + quad) ^ (l15 & 7)) * 8));
#pragma unroll
        for (int it = 0; it < 2; ++it)
          s[it][jt] = __builtin_amdgcn_mfma_f32_16x16x32_bf16(kf, qf[it][ks], s[it][jt], 0, 0, 0);
      }
    }

    // ---- p = exp2(s); accumulate l; P -> per-wave LDS (b64 writes) ----
#pragma unroll
    for (int it = 0; it < 2; ++it) {
#pragma unroll
      for (int jt = 0; jt < 8; ++jt) {
#pragma unroll
        for (int r = 0; r < 4; ++r) s[it][jt][r] = EXP2(s[it][jt][r]);
        *(uint2*)(Pw + (it * 16 + l15) * 136 + jt * 16 + quad * 4) = pk4(s[it][jt]);
      }
      fx4 t0 = (s[it][0] + s[it][1]) + (s[it][2] + s[it][3]);
      fx4 t1 = (s[it][4] + s[it][5]) + (s[it][6] + s[it][7]);
      lacc[it] += t0 + t1;
    }

    // ---- O^T += V^T · P^T : each vf read feeds both groups ----
#pragma unroll
    for (int kj = 0; kj < 4; ++kj) {
      bf16x8 pf[2];
#pragma unroll
      for (int it = 0; it < 2; ++it)
        pf[it] = *(const bf16x8*)(Pw + (it * 16 + l15) * 136 + kj * 32 + quad * 8);
#pragma unroll
      for (int dt = 0; dt < 4; ++dt) {
        bf16x8 vf = *(const bf16x8*)(Vs + (dt * 16 + l15) * 128 + (((kj * 4 + quad) ^ l15) * 8));
#pragma unroll
        for (int it = 0; it < 2; ++it)
          oacc[it][dt] = __builtin_amdgcn_mfma_f32_16x16x32_bf16(vf, pf[it], oacc[it][dt], 0, 0, 0);
      }
    }
  }

  // ---- normalize + write O bf16 [b][n=i][h*64+d]; 4 consecutive d -> b64 ----
#pragma unroll
  for (int it = 0; it < 2; ++it) {
    float l_s = (lacc[it][0] + lacc[it][1]) + (lacc[it][2] + lacc[it][3]);
    l_s += __shfl_xor(l_s, 16);
    l_s += __shfl_xor(l_s, 32);
    float inv = __builtin_amdgcn_rcpf(l_s);
    size_t rowbase = ((size_t)b * 2048 + i0 + it * 16 + l15) * 512 + h * 64;
#pragma unroll
    for (int dt = 0; dt < 4; ++dt) {
      fx4 o = oacc[it][dt] * inv;
      *(uint2*)(O + rowbase + dt * 16 + quad * 4) = pk4(o);
    }
  }
}

// ---------- launch ----------
extern "C" void kernel_launch(void* const* d_in, const int* in_sizes, int n_in,
                              void* d_out, int out_size, void* d_ws, size_t ws_size,
                              hipStream_t stream) {
  const float* x   = (const float*)d_in[0];
  const float* Wq  = (const float*)d_in[1];
  const float* Wkv = (const float*)d_in[2];
  const float* Wo  = (const float*)d_in[3];
  const float* bo  = (const float*)d_in[4];
  float* out = (float*)d_out;

  char* p = (char*)d_ws;
  short* xb    = (short*)p; p += (size_t)8192 * 512 * 2;   // x bf16 [8192,512]
  short* WallT = (short*)p; p += (size_t)1536 * 512 * 2;   // [Wq|Wkv]^T bf16 [1536,512]
  short* WoT   = (short*)p; p += (size_t)512 * 512 * 2;    // Wo^T bf16 [512,512]
  short* qb    = (short*)p; p += (size_t)32 * 2048 * 64 * 2;  // [bh,n,d]
  short* kb    = (short*)p; p += (size_t)32 * 2048 * 64 * 2;  // [bh,n,d]
  short* vTb   = (short*)p; p += (size_t)32 * 64 * 2048 * 2;  // [bh,d,n]
  short* Ob    = (short*)p; p += (size_t)8192 * 512 * 2;   // attn out bf16 [8192,512]

  const float qscale = 0.125f * 1.4426950408889634f;  // d^-0.5 * log2(e)

  prep_kernel<<<5120, 256, 0, stream>>>(x, Wq, Wkv, Wo, xb, WallT, WoT, qscale);
  gemm_qkv<<<dim3(64, 12), 256, 0, stream>>>(xb, WallT, qb, kb, vTb);
  attn_kernel<<<dim3(16, 32), 256, 0, stream>>>(qb, kb, vTb, Ob);
  gemm_out<<<dim3(128, 4), 256, 0, stream>>>(Ob, WoT, out, bo);
}